// Round 1
// baseline (1095.983 us; speedup 1.0000x reference)
//
#include <hip/hip_runtime.h>

typedef unsigned short u16;
typedef unsigned int u32;
typedef __bf16 bf16x8 __attribute__((ext_vector_type(8)));
typedef float f32x4 __attribute__((ext_vector_type(4)));

#define NPIX 100352   // 8*112*112 tokens
#define CDIM 384

static __device__ __forceinline__ u16 f2bf(float f) {
  union { float f; u32 u; } un; un.f = f;
  u32 u = un.u;
  return (u16)((u + 0x7fffu + ((u >> 16) & 1u)) >> 16);
}

static __device__ __forceinline__ f32x4 mfma_bf16(bf16x8 a, bf16x8 b, f32x4 c) {
  return __builtin_amdgcn_mfma_f32_16x16x32_bf16(a, b, c, 0, 0, 0);
}

// ---------------- K0: fp32 -> bf16 weight convert with optional zero padding
__global__ __launch_bounds__(256) void k_pad_bf16(const float* __restrict__ src,
                                                  u16* __restrict__ dst,
                                                  int R, int Csrc, int Rp, int Cp) {
  int idx = blockIdx.x * 256 + threadIdx.x;
  if (idx >= Rp * Cp) return;
  int r = idx / Cp, c = idx - r * Cp;
  float v = (r < R && c < Csrc) ? src[r * Csrc + c] : 0.f;
  dst[idx] = f2bf(v);
}

// ---------------- K1: gather/transpose x[B,C,H,W] -> xw[t, c] (window-token order)
__global__ __launch_bounds__(256) void k_gather(const float* __restrict__ x,
                                                float* __restrict__ xw_f32,
                                                u16* __restrict__ xw_bf16) {
  int bid = blockIdx.x;
  int cg = bid % 6;            // channel group of 64
  int tmp = bid / 6;
  int hh = tmp % 112;
  int b = tmp / 112;
  __shared__ float tile[64][113];
  int tid = threadIdx.x;
  const float* src = x + (((size_t)b * 384 + cg * 64) * 112 + hh) * 112;
  for (int idx = tid; idx < 64 * 112; idx += 256) {
    int c = idx / 112, w = idx - c * 112;
    tile[c][w] = src[(size_t)c * 12544 + w];
  }
  __syncthreads();
  int wh = hh / 7, i = hh - wh * 7;
  for (int idx = tid; idx < 64 * 112; idx += 256) {
    int w = idx >> 6, c = idx & 63;
    int ww = w / 7, j = w - ww * 7;
    size_t t = (((size_t)b * 16 + wh) * 16 + ww) * 49 + i * 7 + j;
    float v = tile[c][w];
    size_t o = t * 384 + cg * 64 + c;
    xw_f32[o] = v;
    xw_bf16[o] = f2bf(v);
  }
}

// ---------------- K9: scatter tmp[t,c] -> out[B,C,H,W]
__global__ __launch_bounds__(256) void k_scatter(const float* __restrict__ t_in,
                                                 float* __restrict__ out) {
  int bid = blockIdx.x;
  int cg = bid % 6;
  int tmp = bid / 6;
  int hh = tmp % 112;
  int b = tmp / 112;
  __shared__ float tile[64][113];
  int tid = threadIdx.x;
  int wh = hh / 7, i = hh - wh * 7;
  for (int idx = tid; idx < 64 * 112; idx += 256) {
    int w = idx >> 6, c = idx & 63;
    int ww = w / 7, j = w - ww * 7;
    size_t t = (((size_t)b * 16 + wh) * 16 + ww) * 49 + i * 7 + j;
    tile[c][w] = t_in[t * 384 + cg * 64 + c];
  }
  __syncthreads();
  float* dst = out + (((size_t)b * 384 + cg * 64) * 112 + hh) * 112;
  for (int idx = tid; idx < 64 * 112; idx += 256) {
    int c = idx / 112, w = idx - c * 112;
    dst[(size_t)c * 12544 + w] = tile[c][w];
  }
}

// ---------------- GEMM: C[m,n] = sum_k A[m,k]*B[n,k] + bias[n]  (A,B bf16 row-major K-major)
// 128x128 tile, 4 waves (2x2), each 64x64 via 4x4 frags of 16x16x32 MFMA, BK=64.
template <int OUT_BF16, int MISH>
__global__ __launch_bounds__(256) void k_gemm(const u16* __restrict__ A,
                                              const u16* __restrict__ B,
                                              const float* __restrict__ bias, int bias_n,
                                              void* __restrict__ C, int K, int ldc) {
  __shared__ u16 lA[128 * 64];
  __shared__ u16 lB[128 * 64];
  int tid = threadIdx.x;
  int m0 = blockIdx.x * 128;
  int n0 = blockIdx.y * 128;
  int wave = tid >> 6, lane = tid & 63;
  int wr = wave >> 1, wc = wave & 1;
  int lr = lane & 15, lk = (lane >> 4) << 3;
  f32x4 acc[4][4] = {};
  int kt_n = K >> 6;
  for (int kt = 0; kt < kt_n; ++kt) {
    int k0 = kt << 6;
#pragma unroll
    for (int i = 0; i < 4; ++i) {
      int chunk = i * 256 + tid;            // 0..1023 (16B chunks)
      int row = chunk >> 3, c8 = (chunk & 7) << 3;
      *(uint4*)(&lA[(row << 6) + c8]) = *(const uint4*)(A + (size_t)(m0 + row) * K + k0 + c8);
      *(uint4*)(&lB[(row << 6) + c8]) = *(const uint4*)(B + (size_t)(n0 + row) * K + k0 + c8);
    }
    __syncthreads();
#pragma unroll
    for (int ks = 0; ks < 2; ++ks) {
      bf16x8 af[4], bf[4];
#pragma unroll
      for (int f = 0; f < 4; ++f) {
        af[f] = *(const bf16x8*)(&lA[((wr * 64 + f * 16 + lr) << 6) + ks * 32 + lk]);
        bf[f] = *(const bf16x8*)(&lB[((wc * 64 + f * 16 + lr) << 6) + ks * 32 + lk]);
      }
#pragma unroll
      for (int fm = 0; fm < 4; ++fm)
#pragma unroll
        for (int fn = 0; fn < 4; ++fn)
          acc[fm][fn] = mfma_bf16(af[fm], bf[fn], acc[fm][fn]);
    }
    __syncthreads();
  }
  int lg = lane >> 4;
#pragma unroll
  for (int fm = 0; fm < 4; ++fm)
#pragma unroll
    for (int fn = 0; fn < 4; ++fn) {
      int col = n0 + wc * 64 + fn * 16 + lr;
      float bi = (col < bias_n) ? bias[col] : 0.f;
#pragma unroll
      for (int r = 0; r < 4; ++r) {
        int row = m0 + wr * 64 + fm * 16 + lg * 4 + r;
        float v = acc[fm][fn][r] + bi;
        if (MISH) {
          float sp = (v > 20.f) ? v : log1pf(__expf(v));
          v = v * tanhf(sp);
        }
        if (OUT_BF16)
          ((u16*)C)[(size_t)row * ldc + col] = f2bf(v);
        else
          ((float*)C)[(size_t)row * ldc + col] = v;
      }
    }
}

// ---------------- K3: window attention. One wave per (window, head). T=49 pad 64, hd=32.
__global__ __launch_bounds__(256) void k_attn(const u16* __restrict__ qkv,
                                              u16* __restrict__ o) {
  __shared__ u16 VT[4][32 * 64];   // V^T per wave: [d][j]
  __shared__ u16 P[4][64 * 64];    // probs per wave: [q][j]
  int tid = threadIdx.x, wave = tid >> 6, lane = tid & 63;
  int gid = blockIdx.x * 4 + wave;          // < 24576
  int win = gid / 12, head = gid - win * 12;
  size_t tb = (size_t)win * 49;
  const u16* q_base = qkv + tb * 1152 + head * 32;
  const u16* k_base = q_base + 384;
  const u16* v_base = q_base + 768;
  u16* vt = VT[wave];
  u16* pp = P[wave];
  int lr = lane & 15, lg = lane >> 4, lk = lg << 3;

  // stage V^T (zero-pad tokens 49..63)
  {
    int tok = lane;
    if (tok < 49) {
      const u32* vr = (const u32*)(v_base + (size_t)tok * 1152);
#pragma unroll
      for (int q8 = 0; q8 < 4; ++q8) {
        uint4 a = *(const uint4*)(vr + q8 * 4);
        u32 arr[4] = {a.x, a.y, a.z, a.w};
#pragma unroll
        for (int p = 0; p < 4; ++p) {
          int d = q8 * 8 + p * 2;
          vt[d * 64 + tok] = (u16)(arr[p] & 0xffffu);
          vt[(d + 1) * 64 + tok] = (u16)(arr[p] >> 16);
        }
      }
    } else {
#pragma unroll
      for (int d = 0; d < 32; ++d) vt[d * 64 + tok] = 0;
    }
  }

  // QK^T: 4x4 fragments, K=32 (one MFMA each)
  f32x4 sc[4][4] = {};
  {
    bf16x8 qf[4], kf[4];
#pragma unroll
    for (int f = 0; f < 4; ++f) {
      int tq = f * 16 + lr; if (tq > 48) tq = 48;
      qf[f] = *(const bf16x8*)(q_base + (size_t)tq * 1152 + lk);
      kf[f] = *(const bf16x8*)(k_base + (size_t)tq * 1152 + lk);
    }
#pragma unroll
    for (int fm = 0; fm < 4; ++fm)
#pragma unroll
      for (int fn = 0; fn < 4; ++fn)
        sc[fm][fn] = mfma_bf16(qf[fm], kf[fn], sc[fm][fn]);
  }

  // softmax over cols (keys); row r of lane = fm*16 + lg*4 + r, col = fn*16 + lr
  const float scale = 0.17677669529663687f;
  float denom[4][4];
#pragma unroll
  for (int fm = 0; fm < 4; ++fm)
#pragma unroll
    for (int r = 0; r < 4; ++r) {
      float mx = -1e30f;
#pragma unroll
      for (int fn = 0; fn < 4; ++fn) {
        int col = fn * 16 + lr;
        float s = sc[fm][fn][r] * scale;
        if (col >= 49) s = -1e30f;
        sc[fm][fn][r] = s;
        mx = fmaxf(mx, s);
      }
      for (int off = 8; off; off >>= 1) mx = fmaxf(mx, __shfl_xor(mx, off));
      float sum = 0.f;
#pragma unroll
      for (int fn = 0; fn < 4; ++fn) {
        float e = __expf(sc[fm][fn][r] - mx);   // masked cols -> 0
        sc[fm][fn][r] = e;
        sum += e;
      }
      for (int off = 8; off; off >>= 1) sum += __shfl_xor(sum, off);
      denom[fm][r] = sum;
    }

  // write P (bf16, unnormalized)
#pragma unroll
  for (int fm = 0; fm < 4; ++fm)
#pragma unroll
    for (int fn = 0; fn < 4; ++fn) {
      int col = fn * 16 + lr;
#pragma unroll
      for (int r = 0; r < 4; ++r) {
        int row = fm * 16 + lg * 4 + r;
        pp[row * 64 + col] = f2bf(sc[fm][fn][r]);
      }
    }
  __syncthreads();

  // PV: M=64, N=32, K=64
  f32x4 oa[4][2] = {};
#pragma unroll
  for (int ks = 0; ks < 2; ++ks) {
    bf16x8 pf[4], vf[2];
#pragma unroll
    for (int f = 0; f < 4; ++f)
      pf[f] = *(const bf16x8*)(&pp[(f * 16 + lr) * 64 + ks * 32 + lk]);
#pragma unroll
    for (int f = 0; f < 2; ++f)
      vf[f] = *(const bf16x8*)(&vt[(f * 16 + lr) * 64 + ks * 32 + lk]);
#pragma unroll
    for (int fm = 0; fm < 4; ++fm)
#pragma unroll
      for (int fn = 0; fn < 2; ++fn)
        oa[fm][fn] = mfma_bf16(pf[fm], vf[fn], oa[fm][fn]);
  }

  // store (divide by softmax denom)
#pragma unroll
  for (int fm = 0; fm < 4; ++fm)
#pragma unroll
    for (int fn = 0; fn < 2; ++fn)
#pragma unroll
      for (int r = 0; r < 4; ++r) {
        int q = fm * 16 + lg * 4 + r;
        if (q < 49) {
          float v = oa[fm][fn][r] / denom[fm][r];
          int d = fn * 16 + lr;
          o[(tb + q) * 384 + head * 32 + d] = f2bf(v);
        }
      }
}

// ---------------- K5/K8: y = LN(a + bres) * g + be ; optional bf16 copy. Wave per token.
template <int WRITE_BF16>
__global__ __launch_bounds__(256) void k_ln(const float* __restrict__ a,
                                            const float* __restrict__ bres,
                                            const float* __restrict__ g,
                                            const float* __restrict__ be,
                                            float* __restrict__ yf,
                                            u16* __restrict__ yb) {
  int wave = threadIdx.x >> 6, lane = threadIdx.x & 63;
  size_t t = (size_t)blockIdx.x * 4 + wave;
  const float* ar = a + t * 384;
  const float* br = bres + t * 384;
  float v[6];
  float s = 0.f, s2 = 0.f;
#pragma unroll
  for (int p = 0; p < 3; ++p) {
    int idx = p * 128 + lane * 2;
    float2 x1 = *(const float2*)(ar + idx);
    float2 x2 = *(const float2*)(br + idx);
    float a0 = x1.x + x2.x, a1 = x1.y + x2.y;
    v[p * 2] = a0; v[p * 2 + 1] = a1;
    s += a0 + a1; s2 += a0 * a0 + a1 * a1;
  }
  for (int off = 32; off; off >>= 1) {
    s += __shfl_xor(s, off);
    s2 += __shfl_xor(s2, off);
  }
  float mean = s * (1.f / 384.f);
  float var = s2 * (1.f / 384.f) - mean * mean;
  float rs = rsqrtf(var + 1e-5f);
  float* yr = yf + t * 384;
#pragma unroll
  for (int p = 0; p < 3; ++p) {
    int idx = p * 128 + lane * 2;
    float2 gg = *(const float2*)(g + idx);
    float2 bb = *(const float2*)(be + idx);
    float y0 = (v[p * 2] - mean) * rs * gg.x + bb.x;
    float y1 = (v[p * 2 + 1] - mean) * rs * gg.y + bb.y;
    *(float2*)(yr + idx) = make_float2(y0, y1);
    if (WRITE_BF16) {
      u32 pk = (u32)f2bf(y0) | ((u32)f2bf(y1) << 16);
      *(u32*)(yb + t * 384 + idx) = pk;
    }
  }
}

extern "C" void kernel_launch(void* const* d_in, const int* in_sizes, int n_in,
                              void* d_out, int out_size, void* d_ws, size_t ws_size,
                              hipStream_t stream) {
  const float* x     = (const float*)d_in[0];
  const float* w_qkv = (const float*)d_in[1];
  const float* b_qkv = (const float*)d_in[2];
  const float* w_o   = (const float*)d_in[3];
  const float* b_o   = (const float*)d_in[4];
  const float* w_c1  = (const float*)d_in[5];
  const float* b_c1  = (const float*)d_in[6];
  const float* w_c2  = (const float*)d_in[7];
  const float* b_c2  = (const float*)d_in[8];
  const float* g1    = (const float*)d_in[9];
  const float* be1   = (const float*)d_in[10];
  const float* g2    = (const float*)d_in[11];
  const float* be2   = (const float*)d_in[12];

  char* ws = (char*)d_ws;
  // arena 1: [0, 154.1MB)  xw_f32 -> y_f32 (in-place) -> ln2 out (in-place)
  float* xw_f32 = (float*)ws;
  // arena 2: [154.1MB, 231.2MB)  xw_bf16 -> o_bf16 -> y_bf16
  u16* xw_bf16 = (u16*)(ws + 154140672);
  // arena 3: [231.2MB, 462.4MB)  qkv -> attn_out_f32 -> {h1, h}
  char* reg3 = ws + 231211008;
  u16* qkv = (u16*)reg3;
  float* attn = (float*)reg3;
  u16* h1 = (u16*)reg3;                       // [NPIX,128] bf16 (25.7MB)
  float* hbuf = (float*)(reg3 + 25690112);    // [NPIX,384] f32
  // weights (bf16) at 462.4MB
  u16* wq_b  = (u16*)(ws + 462422016);
  u16* wo_b  = (u16*)(ws + 463306752);
  u16* wc1_b = (u16*)(ws + 463601664);
  u16* wc2_b = (u16*)(ws + 463699968);
  u16* o_b = xw_bf16;   // alias arena 2
  u16* y_b = xw_bf16;   // alias arena 2

  // weight conversion
  k_pad_bf16<<<1728, 256, 0, stream>>>(w_qkv, wq_b, 1152, 384, 1152, 384);
  k_pad_bf16<<<576, 256, 0, stream>>>(w_o, wo_b, 384, 384, 384, 384);
  k_pad_bf16<<<192, 256, 0, stream>>>(w_c1, wc1_b, 96, 384, 128, 384);
  k_pad_bf16<<<192, 256, 0, stream>>>(w_c2, wc2_b, 384, 96, 384, 128);

  // gather x -> token-major
  k_gather<<<5376, 256, 0, stream>>>(x, xw_f32, xw_bf16);

  // QKV projection: [100352,384] x [1152,384]^T -> bf16 [100352,1152]
  k_gemm<1, 0><<<dim3(784, 9), 256, 0, stream>>>(xw_bf16, wq_b, b_qkv, 1152, (void*)qkv, 384, 1152);

  // attention
  k_attn<<<6144, 256, 0, stream>>>(qkv, o_b);

  // out projection -> f32 attn_out
  k_gemm<0, 0><<<dim3(784, 3), 256, 0, stream>>>(o_b, wo_b, b_o, 384, (void*)attn, 384, 384);

  // residual + LN1 -> y (f32 in-place arena1, bf16 arena2)
  k_ln<1><<<25088, 256, 0, stream>>>(xw_f32, attn, g1, be1, xw_f32, y_b);

  // MLP c1 + Mish -> h1 bf16 [NPIX,128] (cols 96..127 exactly 0)
  k_gemm<1, 1><<<dim3(784, 1), 256, 0, stream>>>(y_b, wc1_b, b_c1, 96, (void*)h1, 384, 128);

  // MLP c2 -> f32 h [NPIX,384]
  k_gemm<0, 0><<<dim3(784, 3), 256, 0, stream>>>(h1, wc2_b, b_c2, 384, (void*)hbuf, 128, 384);

  // residual + LN2 -> arena1 in-place
  k_ln<0><<<25088, 256, 0, stream>>>(xw_f32, hbuf, g2, be2, xw_f32, (u16*)nullptr);

  // scatter to (B,C,H,W)
  k_scatter<<<5376, 256, 0, stream>>>(xw_f32, (float*)d_out);
}

// Round 4
// 1059.849 us; speedup vs baseline: 1.0341x; 1.0341x over previous
//
#include <hip/hip_runtime.h>

typedef unsigned short u16;
typedef unsigned int u32;
typedef __bf16 bf16x8 __attribute__((ext_vector_type(8)));
typedef float f32x4 __attribute__((ext_vector_type(4)));

#define NPIX 100352   // 8*112*112 tokens
#define CDIM 384

static __device__ __forceinline__ u16 f2bf(float f) {
  union { float f; u32 u; } un; un.f = f;
  u32 u = un.u;
  return (u16)((u + 0x7fffu + ((u >> 16) & 1u)) >> 16);
}

static __device__ __forceinline__ f32x4 mfma_bf16(bf16x8 a, bf16x8 b, f32x4 c) {
  return __builtin_amdgcn_mfma_f32_16x16x32_bf16(a, b, c, 0, 0, 0);
}

// async global->LDS, 16B per lane; lds dest must be wave-uniform base (HW adds lane*16)
static __device__ __forceinline__ void gload_lds16(const u16* g, u16* l) {
  __builtin_amdgcn_global_load_lds((const __attribute__((address_space(1))) void*)g,
                                   (__attribute__((address_space(3))) void*)l, 16, 0, 0);
}

// ---------------- K0: fp32 -> bf16 weight convert with optional zero padding
__global__ __launch_bounds__(256) void k_pad_bf16(const float* __restrict__ src,
                                                  u16* __restrict__ dst,
                                                  int R, int Csrc, int Rp, int Cp) {
  int idx = blockIdx.x * 256 + threadIdx.x;
  if (idx >= Rp * Cp) return;
  int r = idx / Cp, c = idx - r * Cp;
  float v = (r < R && c < Csrc) ? src[r * Csrc + c] : 0.f;
  dst[idx] = f2bf(v);
}

// ---------------- K1: gather/transpose x[B,C,H,W] -> xw[t, c] (window-token order)
__global__ __launch_bounds__(256) void k_gather(const float* __restrict__ x,
                                                float* __restrict__ xw_f32,
                                                u16* __restrict__ xw_bf16) {
  int bid = blockIdx.x;
  int cg = bid % 6;            // channel group of 64
  int tmp = bid / 6;
  int hh = tmp % 112;
  int b = tmp / 112;
  __shared__ float tile[64][113];
  int tid = threadIdx.x;
  const float* src = x + (((size_t)b * 384 + cg * 64) * 112 + hh) * 112;
  for (int idx = tid; idx < 64 * 112; idx += 256) {
    int c = idx / 112, w = idx - c * 112;
    tile[c][w] = src[(size_t)c * 12544 + w];
  }
  __syncthreads();
  int wh = hh / 7, i = hh - wh * 7;
  for (int idx = tid; idx < 64 * 112; idx += 256) {
    int w = idx >> 6, c = idx & 63;
    int ww = w / 7, j = w - ww * 7;
    size_t t = (((size_t)b * 16 + wh) * 16 + ww) * 49 + i * 7 + j;
    float v = tile[c][w];
    size_t o = t * 384 + cg * 64 + c;
    xw_f32[o] = v;
    xw_bf16[o] = f2bf(v);
  }
}

// ---------------- K9: scatter tmp[t,c] -> out[B,C,H,W]
__global__ __launch_bounds__(256) void k_scatter(const float* __restrict__ t_in,
                                                 float* __restrict__ out) {
  int bid = blockIdx.x;
  int cg = bid % 6;
  int tmp = bid / 6;
  int hh = tmp % 112;
  int b = tmp / 112;
  __shared__ float tile[64][113];
  int tid = threadIdx.x;
  int wh = hh / 7, i = hh - wh * 7;
  for (int idx = tid; idx < 64 * 112; idx += 256) {
    int w = idx >> 6, c = idx & 63;
    int ww = w / 7, j = w - ww * 7;
    size_t t = (((size_t)b * 16 + wh) * 16 + ww) * 49 + i * 7 + j;
    tile[c][w] = t_in[t * 384 + cg * 64 + c];
  }
  __syncthreads();
  float* dst = out + (((size_t)b * 384 + cg * 64) * 112 + hh) * 112;
  for (int idx = tid; idx < 64 * 112; idx += 256) {
    int c = idx / 112, w = idx - c * 112;
    dst[(size_t)c * 12544 + w] = tile[c][w];
  }
}

// ---------------- GEMM: C[m,n] = sum_k A[m,k]*B[n,k] + bias[n]  (A,B bf16 row-major K-major)
// 128x128 tile, 4 waves (2x2), 64x64/wave via 4x4 frags of 16x16x32 MFMA, BK=64.
// global_load_lds staging (linear LDS dest) + inverse-swizzled global source,
// XOR-swizzled ds_read (chunk ^= row&7 within each 64-elem row). Grid: x=N (fast), y=M,
// XCD-chunked bijective swizzle (nwg % 8 == 0 for all call sites).
template <int OUT_BF16, int MISH>
__global__ __launch_bounds__(256) void k_gemm(const u16* __restrict__ A,
                                              const u16* __restrict__ B,
                                              const float* __restrict__ bias, int bias_n,
                                              void* __restrict__ C, int K, int ldc) {
  __shared__ u16 lA[128 * 64];
  __shared__ u16 lB[128 * 64];
  int tid = threadIdx.x;
  int nbn = gridDim.x;
  int nwg = nbn * gridDim.y;
  int id = blockIdx.y * nbn + blockIdx.x;
  int q = nwg >> 3;                       // nwg divisible by 8 at every call site
  int id2 = (id & 7) * q + (id >> 3);     // XCD-chunked, n-fastest within chunk
  int n0 = (id2 % nbn) * 128;
  int m0 = (id2 / nbn) * 128;
  int wave = tid >> 6, lane = tid & 63;
  int wr = wave >> 1, wc = wave & 1;
  int lr = lane & 15, lg = lane >> 4;
  int lrow = lane >> 3, lchunk = lane & 7;
  int csw = (lchunk ^ lrow) << 3;         // inverse-swizzled source chunk (row&7 == lrow)
  int rsw = lr & 7;                       // read-side row&7
  f32x4 acc[4][4] = {};
  int kt_n = K >> 6;
  for (int kt = 0; kt < kt_n; ++kt) {
    int k0 = kt << 6;
#pragma unroll
    for (int i = 0; i < 4; ++i) {
      int r0 = i * 32 + wave * 8;         // multiple of 8
      int row = r0 + lrow;
      gload_lds16(A + (size_t)(m0 + row) * K + k0 + csw, &lA[r0 << 6]);
      gload_lds16(B + (size_t)(n0 + row) * K + k0 + csw, &lB[r0 << 6]);
    }
    __syncthreads();
#pragma unroll
    for (int ks = 0; ks < 2; ++ks) {
      int coff = (((ks << 2) + lg) ^ rsw) << 3;   // swizzled read chunk
      bf16x8 af[4], bf[4];
#pragma unroll
      for (int f = 0; f < 4; ++f) {
        af[f] = *(const bf16x8*)(&lA[((wr * 64 + f * 16 + lr) << 6) + coff]);
        bf[f] = *(const bf16x8*)(&lB[((wc * 64 + f * 16 + lr) << 6) + coff]);
      }
#pragma unroll
      for (int fm = 0; fm < 4; ++fm)
#pragma unroll
        for (int fn = 0; fn < 4; ++fn)
          acc[fm][fn] = mfma_bf16(af[fm], bf[fn], acc[fm][fn]);
    }
    __syncthreads();
  }
#pragma unroll
  for (int fm = 0; fm < 4; ++fm)
#pragma unroll
    for (int fn = 0; fn < 4; ++fn) {
      int col = n0 + wc * 64 + fn * 16 + lr;
      float bi = (col < bias_n) ? bias[col] : 0.f;
#pragma unroll
      for (int r = 0; r < 4; ++r) {
        int row = m0 + wr * 64 + fm * 16 + lg * 4 + r;
        float v = acc[fm][fn][r] + bi;
        if (MISH) {
          float sp = (v > 20.f) ? v : log1pf(__expf(v));
          v = v * tanhf(sp);
        }
        if (OUT_BF16)
          ((u16*)C)[(size_t)row * ldc + col] = f2bf(v);
        else
          ((float*)C)[(size_t)row * ldc + col] = v;
      }
    }
}

// ---------------- K3: window attention. One wave per (window, head). T=49 pad 64, hd=32.
__global__ __launch_bounds__(256) void k_attn(const u16* __restrict__ qkv,
                                              u16* __restrict__ o) {
  __shared__ u16 VT[4][32 * 64];   // V^T per wave: [d][j]
  __shared__ u16 P[4][64 * 64];    // probs per wave: [q][j]
  int tid = threadIdx.x, wave = tid >> 6, lane = tid & 63;
  int gid = blockIdx.x * 4 + wave;          // < 24576
  int win = gid / 12, head = gid - win * 12;
  size_t tb = (size_t)win * 49;
  const u16* q_base = qkv + tb * 1152 + head * 32;
  const u16* k_base = q_base + 384;
  const u16* v_base = q_base + 768;
  u16* vt = VT[wave];
  u16* pp = P[wave];
  int lr = lane & 15, lg = lane >> 4, lk = lg << 3;

  // stage V^T (zero-pad tokens 49..63)
  {
    int tok = lane;
    if (tok < 49) {
      const u32* vr = (const u32*)(v_base + (size_t)tok * 1152);
#pragma unroll
      for (int q8 = 0; q8 < 4; ++q8) {
        uint4 a = *(const uint4*)(vr + q8 * 4);
        u32 arr[4] = {a.x, a.y, a.z, a.w};
#pragma unroll
        for (int p = 0; p < 4; ++p) {
          int d = q8 * 8 + p * 2;
          vt[d * 64 + tok] = (u16)(arr[p] & 0xffffu);
          vt[(d + 1) * 64 + tok] = (u16)(arr[p] >> 16);
        }
      }
    } else {
#pragma unroll
      for (int d = 0; d < 32; ++d) vt[d * 64 + tok] = 0;
    }
  }

  // QK^T: 4x4 fragments, K=32 (one MFMA each)
  f32x4 sc[4][4] = {};
  {
    bf16x8 qf[4], kf[4];
#pragma unroll
    for (int f = 0; f < 4; ++f) {
      int tq = f * 16 + lr; if (tq > 48) tq = 48;
      qf[f] = *(const bf16x8*)(q_base + (size_t)tq * 1152 + lk);
      kf[f] = *(const bf16x8*)(k_base + (size_t)tq * 1152 + lk);
    }
#pragma unroll
    for (int fm = 0; fm < 4; ++fm)
#pragma unroll
      for (int fn = 0; fn < 4; ++fn)
        sc[fm][fn] = mfma_bf16(qf[fm], kf[fn], sc[fm][fn]);
  }

  // softmax over cols (keys); row r of lane = fm*16 + lg*4 + r, col = fn*16 + lr
  const float scale = 0.17677669529663687f;
  float denom[4][4];
#pragma unroll
  for (int fm = 0; fm < 4; ++fm)
#pragma unroll
    for (int r = 0; r < 4; ++r) {
      float mx = -1e30f;
#pragma unroll
      for (int fn = 0; fn < 4; ++fn) {
        int col = fn * 16 + lr;
        float s = sc[fm][fn][r] * scale;
        if (col >= 49) s = -1e30f;
        sc[fm][fn][r] = s;
        mx = fmaxf(mx, s);
      }
      for (int off = 8; off; off >>= 1) mx = fmaxf(mx, __shfl_xor(mx, off));
      float sum = 0.f;
#pragma unroll
      for (int fn = 0; fn < 4; ++fn) {
        float e = __expf(sc[fm][fn][r] - mx);   // masked cols -> 0
        sc[fm][fn][r] = e;
        sum += e;
      }
      for (int off = 8; off; off >>= 1) sum += __shfl_xor(sum, off);
      denom[fm][r] = sum;
    }

  // write P (bf16, unnormalized)
#pragma unroll
  for (int fm = 0; fm < 4; ++fm)
#pragma unroll
    for (int fn = 0; fn < 4; ++fn) {
      int col = fn * 16 + lr;
#pragma unroll
      for (int r = 0; r < 4; ++r) {
        int row = fm * 16 + lg * 4 + r;
        pp[row * 64 + col] = f2bf(sc[fm][fn][r]);
      }
    }
  __syncthreads();

  // PV: M=64, N=32, K=64
  f32x4 oa[4][2] = {};
#pragma unroll
  for (int ks = 0; ks < 2; ++ks) {
    bf16x8 pf[4], vf[2];
#pragma unroll
    for (int f = 0; f < 4; ++f)
      pf[f] = *(const bf16x8*)(&pp[(f * 16 + lr) * 64 + ks * 32 + lk]);
#pragma unroll
    for (int f = 0; f < 2; ++f)
      vf[f] = *(const bf16x8*)(&vt[(f * 16 + lr) * 64 + ks * 32 + lk]);
#pragma unroll
    for (int fm = 0; fm < 4; ++fm)
#pragma unroll
      for (int fn = 0; fn < 2; ++fn)
        oa[fm][fn] = mfma_bf16(pf[fm], vf[fn], oa[fm][fn]);
  }

  // store (divide by softmax denom)
#pragma unroll
  for (int fm = 0; fm < 4; ++fm)
#pragma unroll
    for (int fn = 0; fn < 2; ++fn)
#pragma unroll
      for (int r = 0; r < 4; ++r) {
        int q = fm * 16 + lg * 4 + r;
        if (q < 49) {
          float v = oa[fm][fn][r] / denom[fm][r];
          int d = fn * 16 + lr;
          o[(tb + q) * 384 + head * 32 + d] = f2bf(v);
        }
      }
}

// ---------------- K5/K8: y = LN(a + bres) * g + be ; optional bf16 copy. Wave per token.
template <int WRITE_BF16>
__global__ __launch_bounds__(256) void k_ln(const float* __restrict__ a,
                                            const float* __restrict__ bres,
                                            const float* __restrict__ g,
                                            const float* __restrict__ be,
                                            float* __restrict__ yf,
                                            u16* __restrict__ yb) {
  int wave = threadIdx.x >> 6, lane = threadIdx.x & 63;
  size_t t = (size_t)blockIdx.x * 4 + wave;
  const float* ar = a + t * 384;
  const float* br = bres + t * 384;
  float v[6];
  float s = 0.f, s2 = 0.f;
#pragma unroll
  for (int p = 0; p < 3; ++p) {
    int idx = p * 128 + lane * 2;
    float2 x1 = *(const float2*)(ar + idx);
    float2 x2 = *(const float2*)(br + idx);
    float a0 = x1.x + x2.x, a1 = x1.y + x2.y;
    v[p * 2] = a0; v[p * 2 + 1] = a1;
    s += a0 + a1; s2 += a0 * a0 + a1 * a1;
  }
  for (int off = 32; off; off >>= 1) {
    s += __shfl_xor(s, off);
    s2 += __shfl_xor(s2, off);
  }
  float mean = s * (1.f / 384.f);
  float var = s2 * (1.f / 384.f) - mean * mean;
  float rs = rsqrtf(var + 1e-5f);
  float* yr = yf + t * 384;
#pragma unroll
  for (int p = 0; p < 3; ++p) {
    int idx = p * 128 + lane * 2;
    float2 gg = *(const float2*)(g + idx);
    float2 bb = *(const float2*)(be + idx);
    float y0 = (v[p * 2] - mean) * rs * gg.x + bb.x;
    float y1 = (v[p * 2 + 1] - mean) * rs * gg.y + bb.y;
    *(float2*)(yr + idx) = make_float2(y0, y1);
    if (WRITE_BF16) {
      u32 pk = (u32)f2bf(y0) | ((u32)f2bf(y1) << 16);
      *(u32*)(yb + t * 384 + idx) = pk;
    }
  }
}

extern "C" void kernel_launch(void* const* d_in, const int* in_sizes, int n_in,
                              void* d_out, int out_size, void* d_ws, size_t ws_size,
                              hipStream_t stream) {
  const float* x     = (const float*)d_in[0];
  const float* w_qkv = (const float*)d_in[1];
  const float* b_qkv = (const float*)d_in[2];
  const float* w_o   = (const float*)d_in[3];
  const float* b_o   = (const float*)d_in[4];
  const float* w_c1  = (const float*)d_in[5];
  const float* b_c1  = (const float*)d_in[6];
  const float* w_c2  = (const float*)d_in[7];
  const float* b_c2  = (const float*)d_in[8];
  const float* g1    = (const float*)d_in[9];
  const float* be1   = (const float*)d_in[10];
  const float* g2    = (const float*)d_in[11];
  const float* be2   = (const float*)d_in[12];

  char* ws = (char*)d_ws;
  // arena 1: [0, 154.1MB)  xw_f32 -> y_f32 (in-place) -> ln2 out (in-place)
  float* xw_f32 = (float*)ws;
  // arena 2: [154.1MB, 231.2MB)  xw_bf16 -> o_bf16 -> y_bf16
  u16* xw_bf16 = (u16*)(ws + 154140672);
  // arena 3: [231.2MB, 462.4MB)  qkv -> attn_out_f32 -> {h1, h}
  char* reg3 = ws + 231211008;
  u16* qkv = (u16*)reg3;
  float* attn = (float*)reg3;
  u16* h1 = (u16*)reg3;                       // [NPIX,128] bf16 (25.7MB)
  float* hbuf = (float*)(reg3 + 25690112);    // [NPIX,384] f32
  // weights (bf16) at 462.4MB
  u16* wq_b  = (u16*)(ws + 462422016);
  u16* wo_b  = (u16*)(ws + 463306752);
  u16* wc1_b = (u16*)(ws + 463601664);
  u16* wc2_b = (u16*)(ws + 463699968);
  u16* o_b = xw_bf16;   // alias arena 2
  u16* y_b = xw_bf16;   // alias arena 2

  // weight conversion
  k_pad_bf16<<<1728, 256, 0, stream>>>(w_qkv, wq_b, 1152, 384, 1152, 384);
  k_pad_bf16<<<576, 256, 0, stream>>>(w_o, wo_b, 384, 384, 384, 384);
  k_pad_bf16<<<192, 256, 0, stream>>>(w_c1, wc1_b, 96, 384, 128, 384);
  k_pad_bf16<<<192, 256, 0, stream>>>(w_c2, wc2_b, 384, 96, 384, 128);

  // gather x -> token-major
  k_gather<<<5376, 256, 0, stream>>>(x, xw_f32, xw_bf16);

  // QKV projection: [100352,384] x [1152,384]^T -> bf16 [100352,1152]
  k_gemm<1, 0><<<dim3(9, 784), 256, 0, stream>>>(xw_bf16, wq_b, b_qkv, 1152, (void*)qkv, 384, 1152);

  // attention
  k_attn<<<6144, 256, 0, stream>>>(qkv, o_b);

  // out projection -> f32 attn_out
  k_gemm<0, 0><<<dim3(3, 784), 256, 0, stream>>>(o_b, wo_b, b_o, 384, (void*)attn, 384, 384);

  // residual + LN1 -> y (f32 in-place arena1, bf16 arena2)
  k_ln<1><<<25088, 256, 0, stream>>>(xw_f32, attn, g1, be1, xw_f32, y_b);

  // MLP c1 + Mish -> h1 bf16 [NPIX,128] (cols 96..127 exactly 0)
  k_gemm<1, 1><<<dim3(1, 784), 256, 0, stream>>>(y_b, wc1_b, b_c1, 96, (void*)h1, 384, 128);

  // MLP c2 -> f32 h [NPIX,384]
  k_gemm<0, 0><<<dim3(3, 784), 256, 0, stream>>>(h1, wc2_b, b_c2, 384, (void*)hbuf, 128, 384);

  // residual + LN2 -> arena1 in-place
  k_ln<0><<<25088, 256, 0, stream>>>(xw_f32, hbuf, g2, be2, xw_f32, (u16*)nullptr);

  // scatter to (B,C,H,W)
  k_scatter<<<5376, 256, 0, stream>>>(xw_f32, (float*)d_out);
}

// Round 7
// 937.699 us; speedup vs baseline: 1.1688x; 1.1303x over previous
//
#include <hip/hip_runtime.h>

typedef unsigned short u16;
typedef unsigned int u32;
typedef __bf16 bf16x8 __attribute__((ext_vector_type(8)));
typedef float f32x4 __attribute__((ext_vector_type(4)));

#define NPIX 100352   // 8*112*112 tokens
#define CDIM 384

static __device__ __forceinline__ u16 f2bf(float f) {
  union { float f; u32 u; } un; un.f = f;
  u32 u = un.u;
  return (u16)((u + 0x7fffu + ((u >> 16) & 1u)) >> 16);
}

static __device__ __forceinline__ f32x4 mfma_bf16(bf16x8 a, bf16x8 b, f32x4 c) {
  return __builtin_amdgcn_mfma_f32_16x16x32_bf16(a, b, c, 0, 0, 0);
}

// async global->LDS, 16B per lane; lds dest must be wave-uniform base (HW adds lane*16)
static __device__ __forceinline__ void gload_lds16(const u16* g, u16* l) {
  __builtin_amdgcn_global_load_lds((const __attribute__((address_space(1))) void*)g,
                                   (__attribute__((address_space(3))) void*)l, 16, 0, 0);
}

// ---------------- K0: fp32 -> bf16 weight convert with optional zero padding
__global__ __launch_bounds__(256) void k_pad_bf16(const float* __restrict__ src,
                                                  u16* __restrict__ dst,
                                                  int R, int Csrc, int Rp, int Cp) {
  int idx = blockIdx.x * 256 + threadIdx.x;
  if (idx >= Rp * Cp) return;
  int r = idx / Cp, c = idx - r * Cp;
  float v = (r < R && c < Csrc) ? src[r * Csrc + c] : 0.f;
  dst[idx] = f2bf(v);
}

// ---------------- K1: gather/transpose x[B,C,H,W] -> xw[t, c] (window-token order)
__global__ __launch_bounds__(256) void k_gather(const float* __restrict__ x,
                                                float* __restrict__ xw_f32,
                                                u16* __restrict__ xw_bf16) {
  int bid = blockIdx.x;
  int cg = bid % 6;            // channel group of 64
  int tmp = bid / 6;
  int hh = tmp % 112;
  int b = tmp / 112;
  __shared__ float tile[64][113];
  int tid = threadIdx.x;
  const float* src = x + (((size_t)b * 384 + cg * 64) * 112 + hh) * 112;
  for (int idx = tid; idx < 64 * 112; idx += 256) {
    int c = idx / 112, w = idx - c * 112;
    tile[c][w] = src[(size_t)c * 12544 + w];
  }
  __syncthreads();
  int wh = hh / 7, i = hh - wh * 7;
  for (int idx = tid; idx < 64 * 112; idx += 256) {
    int w = idx >> 6, c = idx & 63;
    int ww = w / 7, j = w - ww * 7;
    size_t t = (((size_t)b * 16 + wh) * 16 + ww) * 49 + i * 7 + j;
    float v = tile[c][w];
    size_t o = t * 384 + cg * 64 + c;
    xw_f32[o] = v;
    xw_bf16[o] = f2bf(v);
  }
}

// ---------------- K9: scatter tmp[t,c] -> out[B,C,H,W]
__global__ __launch_bounds__(256) void k_scatter(const float* __restrict__ t_in,
                                                 float* __restrict__ out) {
  int bid = blockIdx.x;
  int cg = bid % 6;
  int tmp = bid / 6;
  int hh = tmp % 112;
  int b = tmp / 112;
  __shared__ float tile[64][113];
  int tid = threadIdx.x;
  int wh = hh / 7, i = hh - wh * 7;
  for (int idx = tid; idx < 64 * 112; idx += 256) {
    int w = idx >> 6, c = idx & 63;
    int ww = w / 7, j = w - ww * 7;
    size_t t = (((size_t)b * 16 + wh) * 16 + ww) * 49 + i * 7 + j;
    tile[c][w] = t_in[t * 384 + cg * 64 + c];
  }
  __syncthreads();
  float* dst = out + (((size_t)b * 384 + cg * 64) * 112 + hh) * 112;
  for (int idx = tid; idx < 64 * 112; idx += 256) {
    int c = idx / 112, w = idx - c * 112;
    dst[(size_t)c * 12544 + w] = tile[c][w];
  }
}

// ---------------- GEMM: C[m,n] = sum_k A[m,k]*B[n,k] + bias[n]  (A,B bf16 row-major K-major)
// 128x128 tile, 4 waves (2x2), 64x64/wave via 4x4 frags of 16x16x32 MFMA, BK=64.
// global_load_lds staging (linear LDS dest) + inverse-swizzled global source,
// XOR-swizzled ds_read. Grid: x=N (fast), y=M, XCD-chunked bijective swizzle.
template <int OUT_BF16, int MISH>
__global__ __launch_bounds__(256) void k_gemm(const u16* __restrict__ A,
                                              const u16* __restrict__ B,
                                              const float* __restrict__ bias, int bias_n,
                                              void* __restrict__ C, int K, int ldc) {
  __shared__ u16 lA[128 * 64];
  __shared__ u16 lB[128 * 64];
  int tid = threadIdx.x;
  int nbn = gridDim.x;
  int nwg = nbn * gridDim.y;
  int id = blockIdx.y * nbn + blockIdx.x;
  int q = nwg >> 3;                       // nwg divisible by 8 at every call site
  int id2 = (id & 7) * q + (id >> 3);     // XCD-chunked, n-fastest within chunk
  int n0 = (id2 % nbn) * 128;
  int m0 = (id2 / nbn) * 128;
  int wave = tid >> 6, lane = tid & 63;
  int wr = wave >> 1, wc = wave & 1;
  int lr = lane & 15, lg = lane >> 4;
  int lrow = lane >> 3, lchunk = lane & 7;
  int csw = (lchunk ^ lrow) << 3;         // inverse-swizzled source chunk (row&7 == lrow)
  int rsw = lr & 7;                       // read-side row&7
  f32x4 acc[4][4] = {};
  int kt_n = K >> 6;
  for (int kt = 0; kt < kt_n; ++kt) {
    int k0 = kt << 6;
#pragma unroll
    for (int i = 0; i < 4; ++i) {
      int r0 = i * 32 + wave * 8;         // multiple of 8
      int row = r0 + lrow;
      gload_lds16(A + (size_t)(m0 + row) * K + k0 + csw, &lA[r0 << 6]);
      gload_lds16(B + (size_t)(n0 + row) * K + k0 + csw, &lB[r0 << 6]);
    }
    __syncthreads();
#pragma unroll
    for (int ks = 0; ks < 2; ++ks) {
      int coff = (((ks << 2) + lg) ^ rsw) << 3;   // swizzled read chunk
      bf16x8 af[4], bf[4];
#pragma unroll
      for (int f = 0; f < 4; ++f) {
        af[f] = *(const bf16x8*)(&lA[((wr * 64 + f * 16 + lr) << 6) + coff]);
        bf[f] = *(const bf16x8*)(&lB[((wc * 64 + f * 16 + lr) << 6) + coff]);
      }
#pragma unroll
      for (int fm = 0; fm < 4; ++fm)
#pragma unroll
        for (int fn = 0; fn < 4; ++fn)
          acc[fm][fn] = mfma_bf16(af[fm], bf[fn], acc[fm][fn]);
    }
    __syncthreads();
  }
#pragma unroll
  for (int fm = 0; fm < 4; ++fm)
#pragma unroll
    for (int fn = 0; fn < 4; ++fn) {
      int col = n0 + wc * 64 + fn * 16 + lr;
      float bi = (col < bias_n) ? bias[col] : 0.f;
#pragma unroll
      for (int r = 0; r < 4; ++r) {
        int row = m0 + wr * 64 + fm * 16 + lg * 4 + r;
        float v = acc[fm][fn][r] + bi;
        if (MISH) {
          float sp = (v > 20.f) ? v : log1pf(__expf(v));
          v = v * tanhf(sp);
        }
        if (OUT_BF16)
          ((u16*)C)[(size_t)row * ldc + col] = f2bf(v);
        else
          ((float*)C)[(size_t)row * ldc + col] = v;
      }
    }
}

// ---------------- fused GEMM + bias + residual + LayerNorm.
// C-tile: 64 rows x full N=384. 8 waves, wave w owns cols [w*48, w*48+48).
// y = LN(A@B^T + bias + resid) * g + be ; writes f32 (yf) and optionally bf16 (yb).
// Same staging/swizzle scheme as k_gemm. Grid: NPIX/64 = 1568 blocks (%8==0).
template <int WRITE_BF16>
__global__ __launch_bounds__(512, 4) void k_gemm_ln(const u16* __restrict__ A,
                                                    const u16* __restrict__ B,
                                                    const float* __restrict__ bias,
                                                    const float* __restrict__ resid,
                                                    const float* __restrict__ g,
                                                    const float* __restrict__ be,
                                                    float* __restrict__ yf,
                                                    u16* __restrict__ yb, int K) {
  __shared__ u16 lA[64 * 64];      // 8 KB
  __shared__ u16 lB[384 * 64];     // 48 KB
  __shared__ float redS[8][64], redS2[8][64];
  __shared__ float redM[64], redR[64];
  int tid = threadIdx.x;
  int nwg = gridDim.x;             // 1568
  int id = blockIdx.x;
  int q = nwg >> 3;
  int id2 = (id & 7) * q + (id >> 3);
  int m0 = id2 * 64;
  int wave = tid >> 6, lane = tid & 63;
  int lr = lane & 15, lg = lane >> 4;
  int lchunk = lane & 7;
  int rsw = lr & 7;
  int srow = tid >> 3;             // 0..63 staging row
  f32x4 acc[4][3] = {};
  int kt_n = K >> 6;
  for (int kt = 0; kt < kt_n; ++kt) {
    int k0 = kt << 6;
    // A: one issue covers 64x64 (row = wave*8 + lane>>3; row&7 == lane>>3)
    gload_lds16(A + (size_t)(m0 + srow) * K + k0 + ((lchunk ^ (srow & 7)) << 3),
                &lA[(wave * 8) << 6]);
    // B: 6 issues cover 384x64
#pragma unroll
    for (int i = 0; i < 6; ++i) {
      int row = i * 64 + srow;
      gload_lds16(B + (size_t)row * K + k0 + ((lchunk ^ (srow & 7)) << 3),
                  &lB[(i * 64 + wave * 8) << 6]);
    }
    __syncthreads();
#pragma unroll
    for (int ks = 0; ks < 2; ++ks) {
      int coff = (((ks << 2) + lg) ^ rsw) << 3;
      bf16x8 af[4], bf[3];
#pragma unroll
      for (int f = 0; f < 4; ++f)
        af[f] = *(const bf16x8*)(&lA[((f * 16 + lr) << 6) + coff]);
#pragma unroll
      for (int f = 0; f < 3; ++f)
        bf[f] = *(const bf16x8*)(&lB[((wave * 48 + f * 16 + lr) << 6) + coff]);
#pragma unroll
      for (int fm = 0; fm < 4; ++fm)
#pragma unroll
        for (int fn = 0; fn < 3; ++fn)
          acc[fm][fn] = mfma_bf16(af[fm], bf[fn], acc[fm][fn]);
    }
    __syncthreads();
  }
  // epilogue: z = acc + bias + resid; row stats; LN
  int col0 = wave * 48 + lr;
  float bi[3], gg[3], bb[3];
#pragma unroll
  for (int fn = 0; fn < 3; ++fn) {
    bi[fn] = bias[col0 + fn * 16];
    gg[fn] = g[col0 + fn * 16];
    bb[fn] = be[col0 + fn * 16];
  }
#pragma unroll
  for (int fm = 0; fm < 4; ++fm)
#pragma unroll
    for (int r = 0; r < 4; ++r) {
      int rloc = fm * 16 + lg * 4 + r;
      const float* rr = resid + (size_t)(m0 + rloc) * 384 + col0;
      float s = 0.f, s2 = 0.f;
#pragma unroll
      for (int fn = 0; fn < 3; ++fn) {
        float z = acc[fm][fn][r] + bi[fn] + rr[fn * 16];
        acc[fm][fn][r] = z;
        s += z; s2 += z * z;
      }
#pragma unroll
      for (int off = 1; off < 16; off <<= 1) {
        s += __shfl_xor(s, off);
        s2 += __shfl_xor(s2, off);
      }
      if (lr == 0) { redS[wave][rloc] = s; redS2[wave][rloc] = s2; }
    }
  __syncthreads();
  if (tid < 64) {
    float S = 0.f, S2 = 0.f;
#pragma unroll
    for (int w = 0; w < 8; ++w) { S += redS[w][tid]; S2 += redS2[w][tid]; }
    float mean = S * (1.f / 384.f);
    float var = S2 * (1.f / 384.f) - mean * mean;
    redM[tid] = mean;
    redR[tid] = rsqrtf(var + 1e-5f);
  }
  __syncthreads();
#pragma unroll
  for (int fm = 0; fm < 4; ++fm)
#pragma unroll
    for (int r = 0; r < 4; ++r) {
      int rloc = fm * 16 + lg * 4 + r;
      float mean = redM[rloc], rs = redR[rloc];
      size_t rowo = (size_t)(m0 + rloc) * 384 + col0;
#pragma unroll
      for (int fn = 0; fn < 3; ++fn) {
        float y = (acc[fm][fn][r] - mean) * rs * gg[fn] + bb[fn];
        yf[rowo + fn * 16] = y;
        if (WRITE_BF16) yb[rowo + fn * 16] = f2bf(y);
      }
    }
}

// ---------------- K3: window attention. One wave per (window, head). T=49 pad 64, hd=32.
__global__ __launch_bounds__(256) void k_attn(const u16* __restrict__ qkv,
                                              u16* __restrict__ o) {
  __shared__ u16 VT[4][32 * 64];   // V^T per wave: [d][j]
  __shared__ u16 P[4][64 * 64];    // probs per wave: [q][j]
  int tid = threadIdx.x, wave = tid >> 6, lane = tid & 63;
  int gid = blockIdx.x * 4 + wave;          // < 24576
  int win = gid / 12, head = gid - win * 12;
  size_t tb = (size_t)win * 49;
  const u16* q_base = qkv + tb * 1152 + head * 32;
  const u16* k_base = q_base + 384;
  const u16* v_base = q_base + 768;
  u16* vt = VT[wave];
  u16* pp = P[wave];
  int lr = lane & 15, lg = lane >> 4, lk = lg << 3;

  // stage V^T (zero-pad tokens 49..63)
  {
    int tok = lane;
    if (tok < 49) {
      const u32* vr = (const u32*)(v_base + (size_t)tok * 1152);
#pragma unroll
      for (int q8 = 0; q8 < 4; ++q8) {
        uint4 a = *(const uint4*)(vr + q8 * 4);
        u32 arr[4] = {a.x, a.y, a.z, a.w};
#pragma unroll
        for (int p = 0; p < 4; ++p) {
          int d = q8 * 8 + p * 2;
          vt[d * 64 + tok] = (u16)(arr[p] & 0xffffu);
          vt[(d + 1) * 64 + tok] = (u16)(arr[p] >> 16);
        }
      }
    } else {
#pragma unroll
      for (int d = 0; d < 32; ++d) vt[d * 64 + tok] = 0;
    }
  }

  // QK^T: 4x4 fragments, K=32 (one MFMA each)
  f32x4 sc[4][4] = {};
  {
    bf16x8 qf[4], kf[4];
#pragma unroll
    for (int f = 0; f < 4; ++f) {
      int tq = f * 16 + lr; if (tq > 48) tq = 48;
      qf[f] = *(const bf16x8*)(q_base + (size_t)tq * 1152 + lk);
      kf[f] = *(const bf16x8*)(k_base + (size_t)tq * 1152 + lk);
    }
#pragma unroll
    for (int fm = 0; fm < 4; ++fm)
#pragma unroll
      for (int fn = 0; fn < 4; ++fn)
        sc[fm][fn] = mfma_bf16(qf[fm], kf[fn], sc[fm][fn]);
  }

  // softmax over cols (keys); row r of lane = fm*16 + lg*4 + r, col = fn*16 + lr
  const float scale = 0.17677669529663687f;
  float denom[4][4];
#pragma unroll
  for (int fm = 0; fm < 4; ++fm)
#pragma unroll
    for (int r = 0; r < 4; ++r) {
      float mx = -1e30f;
#pragma unroll
      for (int fn = 0; fn < 4; ++fn) {
        int col = fn * 16 + lr;
        float s = sc[fm][fn][r] * scale;
        if (col >= 49) s = -1e30f;
        sc[fm][fn][r] = s;
        mx = fmaxf(mx, s);
      }
      for (int off = 8; off; off >>= 1) mx = fmaxf(mx, __shfl_xor(mx, off));
      float sum = 0.f;
#pragma unroll
      for (int fn = 0; fn < 4; ++fn) {
        float e = __expf(sc[fm][fn][r] - mx);   // masked cols -> 0
        sc[fm][fn][r] = e;
        sum += e;
      }
      for (int off = 8; off; off >>= 1) sum += __shfl_xor(sum, off);
      denom[fm][r] = sum;
    }

  // write P (bf16, unnormalized)
#pragma unroll
  for (int fm = 0; fm < 4; ++fm)
#pragma unroll
    for (int fn = 0; fn < 4; ++fn) {
      int col = fn * 16 + lr;
#pragma unroll
      for (int r = 0; r < 4; ++r) {
        int row = fm * 16 + lg * 4 + r;
        pp[row * 64 + col] = f2bf(sc[fm][fn][r]);
      }
    }
  __syncthreads();

  // PV: M=64, N=32, K=64
  f32x4 oa[4][2] = {};
#pragma unroll
  for (int ks = 0; ks < 2; ++ks) {
    bf16x8 pf[4], vf[2];
#pragma unroll
    for (int f = 0; f < 4; ++f)
      pf[f] = *(const bf16x8*)(&pp[(f * 16 + lr) * 64 + ks * 32 + lk]);
#pragma unroll
    for (int f = 0; f < 2; ++f)
      vf[f] = *(const bf16x8*)(&vt[(f * 16 + lr) * 64 + ks * 32 + lk]);
#pragma unroll
    for (int fm = 0; fm < 4; ++fm)
#pragma unroll
      for (int fn = 0; fn < 2; ++fn)
        oa[fm][fn] = mfma_bf16(pf[fm], vf[fn], oa[fm][fn]);
  }

  // store (divide by softmax denom)
#pragma unroll
  for (int fm = 0; fm < 4; ++fm)
#pragma unroll
    for (int fn = 0; fn < 2; ++fn)
#pragma unroll
      for (int r = 0; r < 4; ++r) {
        int q = fm * 16 + lg * 4 + r;
        if (q < 49) {
          float v = oa[fm][fn][r] / denom[fm][r];
          int d = fn * 16 + lr;
          o[(tb + q) * 384 + head * 32 + d] = f2bf(v);
        }
      }
}

extern "C" void kernel_launch(void* const* d_in, const int* in_sizes, int n_in,
                              void* d_out, int out_size, void* d_ws, size_t ws_size,
                              hipStream_t stream) {
  const float* x     = (const float*)d_in[0];
  const float* w_qkv = (const float*)d_in[1];
  const float* b_qkv = (const float*)d_in[2];
  const float* w_o   = (const float*)d_in[3];
  const float* b_o   = (const float*)d_in[4];
  const float* w_c1  = (const float*)d_in[5];
  const float* b_c1  = (const float*)d_in[6];
  const float* w_c2  = (const float*)d_in[7];
  const float* b_c2  = (const float*)d_in[8];
  const float* g1    = (const float*)d_in[9];
  const float* be1   = (const float*)d_in[10];
  const float* g2    = (const float*)d_in[11];
  const float* be2   = (const float*)d_in[12];

  char* ws = (char*)d_ws;
  // arena 1: [0, 154.1MB)  xw_f32 -> y_f32 (in-place, fused LN1) -> final (in-place, fused LN2)
  float* xw_f32 = (float*)ws;
  // arena 2: [154.1MB, 231.2MB)  xw_bf16 -> o_bf16 -> y_bf16
  u16* xw_bf16 = (u16*)(ws + 154140672);
  // arena 3: [231.2MB, 462.4MB)  qkv -> h1
  char* reg3 = ws + 231211008;
  u16* qkv = (u16*)reg3;
  u16* h1 = (u16*)reg3;                       // [NPIX,128] bf16 (25.7MB)
  // weights (bf16) at 462.4MB
  u16* wq_b  = (u16*)(ws + 462422016);
  u16* wo_b  = (u16*)(ws + 463306752);
  u16* wc1_b = (u16*)(ws + 463601664);
  u16* wc2_b = (u16*)(ws + 463699968);
  u16* o_b = xw_bf16;   // alias arena 2
  u16* y_b = xw_bf16;   // alias arena 2

  // weight conversion
  k_pad_bf16<<<1728, 256, 0, stream>>>(w_qkv, wq_b, 1152, 384, 1152, 384);
  k_pad_bf16<<<576, 256, 0, stream>>>(w_o, wo_b, 384, 384, 384, 384);
  k_pad_bf16<<<192, 256, 0, stream>>>(w_c1, wc1_b, 96, 384, 128, 384);
  k_pad_bf16<<<192, 256, 0, stream>>>(w_c2, wc2_b, 384, 96, 384, 128);

  // gather x -> token-major
  k_gather<<<5376, 256, 0, stream>>>(x, xw_f32, xw_bf16);

  // QKV projection: [100352,384] x [1152,384]^T -> bf16 [100352,1152]
  k_gemm<1, 0><<<dim3(9, 784), 256, 0, stream>>>(xw_bf16, wq_b, b_qkv, 1152, (void*)qkv, 384, 1152);

  // attention (writes o_b over arena2; xw_bf16 dead after QKV GEMM)
  k_attn<<<6144, 256, 0, stream>>>(qkv, o_b);

  // out projection + bias + residual(x) + LN1 -> y_f32 (in-place arena1) and y_b (in-place arena2)
  k_gemm_ln<1><<<1568, 512, 0, stream>>>(o_b, wo_b, b_o, xw_f32, g1, be1,
                                         xw_f32, y_b, 384);

  // MLP c1 + Mish -> h1 bf16 [NPIX,128] (cols 96..127 exactly 0; qkv dead after attn)
  k_gemm<1, 1><<<dim3(1, 784), 256, 0, stream>>>(y_b, wc1_b, b_c1, 96, (void*)h1, 384, 128);

  // MLP c2 + bias + residual(y) + LN2 -> final f32 (in-place arena1)
  k_gemm_ln<0><<<1568, 512, 0, stream>>>(h1, wc2_b, b_c2, xw_f32, g2, be2,
                                         xw_f32, (u16*)nullptr, 128);

  // scatter to (B,C,H,W)
  k_scatter<<<5376, 256, 0, stream>>>(xw_f32, (float*)d_out);
}